// Round 14
// baseline (6310.326 us; speedup 1.0000x reference)
//
#include <hip/hip_runtime.h>
#include <hip/hip_bf16.h>
#include <stdint.h>

#define T_STEPS 512
#define NBATCH 64
#define HID 1024
#define NGATE 4096
#define NLAYERS 2
#define BH (NBATCH * HID)            // 65536
#define TBH (T_STEPS * NBATCH * HID) // 33554432
#define WEL ((size_t)NLAYERS * NGATE * HID)
#define GBLK 128                     // blocks per barrier group

typedef __attribute__((ext_vector_type(8))) short short8;
typedef __attribute__((ext_vector_type(16))) float f32x16;

__device__ __forceinline__ ushort f2bf(float f) {
  union { float f; uint32_t i; } u; u.f = f;
  return (ushort)((u.i + 0x7fffu + ((u.i >> 16) & 1u)) >> 16);  // RNE
}
__device__ __forceinline__ void gll16(const void* g, void* l) {
  __builtin_amdgcn_global_load_lds(
      (const __attribute__((address_space(1))) unsigned int*)g,
      (__attribute__((address_space(3))) unsigned int*)l, 16, 0, 0);
}

// ---- per-wave A-load pipe: 16 rotating slots, counted vmcnt (r7-proven).
// All cached loads (x, h0 ring, h1 ring: never rewritten within dispatch).
#define ISS(S, OFF) \
  asm volatile("global_load_dwordx4 %0, %1, off offset:" #OFF \
               : "=v"(fr[S]) : "v"(aPtr));
#define VMW(N, SLOT) \
  asm volatile("s_waitcnt vmcnt(" #N ")" : "+v"(fr[SLOT]));
#define CONS(S, KC) { \
    const short8 bv = *(const short8*)(bB + (KC) * 1024); \
    acc = __builtin_amdgcn_mfma_f32_32x32x16_bf16(fr[S], bv, acc, 0, 0, 0); }

// 32 loads / 32 MFMAs of 32x32x16 per wave-step (K=512 slice).
#define PIPE32X() \
  ISS(0,0)   ISS(1,32)  ISS(2,64)  ISS(3,96)  ISS(4,128) ISS(5,160) ISS(6,192) ISS(7,224) \
  ISS(8,256) ISS(9,288) ISS(10,320) ISS(11,352) ISS(12,384) ISS(13,416) ISS(14,448) ISS(15,480) \
  VMW(15,0)  CONS(0,0)   ISS(0,512)  \
  VMW(15,1)  CONS(1,1)   ISS(1,544)  \
  VMW(15,2)  CONS(2,2)   ISS(2,576)  \
  VMW(15,3)  CONS(3,3)   ISS(3,608)  \
  VMW(15,4)  CONS(4,4)   ISS(4,640)  \
  VMW(15,5)  CONS(5,5)   ISS(5,672)  \
  VMW(15,6)  CONS(6,6)   ISS(6,704)  \
  VMW(15,7)  CONS(7,7)   ISS(7,736)  \
  VMW(15,8)  CONS(8,8)   ISS(8,768)  \
  VMW(15,9)  CONS(9,9)   ISS(9,800)  \
  VMW(15,10) CONS(10,10) ISS(10,832) \
  VMW(15,11) CONS(11,11) ISS(11,864) \
  VMW(15,12) CONS(12,12) ISS(12,896) \
  VMW(15,13) CONS(13,13) ISS(13,928) \
  VMW(15,14) CONS(14,14) ISS(14,960) \
  VMW(15,15) CONS(15,15) ISS(15,992) \
  VMW(15,0)  CONS(0,16)  \
  VMW(14,1)  CONS(1,17)  \
  VMW(13,2)  CONS(2,18)  \
  VMW(12,3)  CONS(3,19)  \
  VMW(11,4)  CONS(4,20)  \
  VMW(10,5)  CONS(5,21)  \
  VMW(9,6)   CONS(6,22)  \
  VMW(8,7)   CONS(7,23)  \
  VMW(7,8)   CONS(8,24)  \
  VMW(6,9)   CONS(9,25)  \
  VMW(5,10)  CONS(10,26) \
  VMW(4,11)  CONS(11,27) \
  VMW(3,12)  CONS(12,28) \
  VMW(2,13)  CONS(13,29) \
  VMW(1,14)  CONS(14,30) \
  VMW(0,15)  CONS(15,31)

// ---------------- elementwise helpers ----------------
__global__ void k_f32_to_bf16(const float* __restrict__ in, ushort* __restrict__ out, int n) {
  int i = (blockIdx.x * blockDim.x + threadIdx.x) * 4;
  if (i >= n) return;
  const float4 v = *reinterpret_cast<const float4*>(in + i);
  ushort4 o; o.x = f2bf(v.x); o.y = f2bf(v.y); o.z = f2bf(v.z); o.w = f2bf(v.w);
  *reinterpret_cast<ushort4*>(out + i) = o;
}
__global__ void k_zero(int* p, int n) {
  int i = blockIdx.x * blockDim.x + threadIdx.x;
  if (i < n) p[i] = 0;
}

// ---------------- persistent fused scan ----------------
struct ScanP {
  const ushort* wih; const ushort* whh;
  const ushort* xb;  const ushort* hinit;
  ushort* h0r;                            // layer-0 h ring (T_STEPS slots)
  ushort* h1r;                            // layer-1 h ring (T_STEPS slots)
  const float* c0; const float* bi; const float* bh;
  float* out; int* bar;
};

// Wave-level gate on a monotonic release word; watermark-cached (seen).
__device__ __forceinline__ void wgate(const int* rel, int target, int& seen) {
  if (seen < target) {
    int v = __hip_atomic_load(rel, __ATOMIC_RELAXED, __HIP_MEMORY_SCOPE_AGENT);
    while (v < target) {
      __builtin_amdgcn_s_sleep(2);
      v = __hip_atomic_load(rel, __ATOMIC_RELAXED, __HIP_MEMORY_SCOPE_AGENT);
    }
    seen = v;
    __builtin_amdgcn_sched_barrier(0);
  }
}

// 256 blocks x 512 threads (8 waves, 2/SIMD). Blocks 0..127 = layer 0; 128..255
// = layer 1. Wave w -> (Mtile = w>>2: batch half, quarter = w&3: K-slice of 512;
// quarters 0,1 read src0 (x_t / h0[t]), quarters 2,3 read src1 (h-prev)).
// W in LDS chunk-major [kchunk][row] (16B units): staging AND B-reads phase-
// conflict-free. K-split partials reduced via deterministic pairwise LDS tree.
__global__ __launch_bounds__(512, 2) void k_scan(ScanP p) {
  __shared__ __align__(16) ushort Wl[256 * 256];   // 128 KB: chunk c at c*512B + r*16B
  __shared__ float glds[4][32][36];                // partial/final slots, 18.4 KB
  const int tid = threadIdx.x, wave = tid >> 6, lane = tid & 63;
  const bool isL1 = blockIdx.x >= 128;
  const int cb = isL1 ? (int)blockIdx.x - 128 : (int)blockIdx.x;
  const int j0 = cb * 8;
  const int stripe = cb & 15;
  const bool isRoot = (cb == 0);
  int* gb = p.bar + (isL1 ? 512 : 0);
  const int* rel0 = p.bar + 256;
  const int* rel1 = p.bar + 768;
  int* relOwn = p.bar + (isL1 ? 768 : 256);
  const int Mtile = wave >> 2, quarter = wave & 3;

  // ---- stage W (fused [W_ih | W_hh] rows) chunk-major, once ----
  const ushort* wihL = p.wih + (isL1 ? (size_t)NGATE * HID : 0);
  const ushort* whhL = p.whh + (isL1 ? (size_t)NGATE * HID : 0);
  {
    const int r = lane & 31;
    const int grow = (r >> 3) * 1024 + j0 + (r & 7);
    for (int inst = wave; inst < 128; inst += 8) {
      const int c0 = inst * 2;
      const ushort* basew = (c0 < 128) ? wihL : whhL;
      const ushort* gsrc = basew + (size_t)grow * 1024 + ((c0 & 127) + (lane >> 5)) * 8;
      gll16(gsrc, (char*)Wl + inst * 1024);
    }
  }

  // ---- epilogue geometry: thread -> one (b = tid>>3, jl = tid&7) ----
  const int eb = tid >> 3, jl = tid & 7, jj = j0 + jl;
  const int tile = eb >> 5, row = eb & 31;
  const int lofs = isL1 ? NGATE : 0;
  float creg = p.c0[(isL1 ? BH : 0) + eb * 1024 + jj];
  float bias[4];
#pragma unroll
  for (int g = 0; g < 4; ++g)
    bias[g] = p.bi[lofs + g * 1024 + jj] + p.bh[lofs + g * 1024 + jj];

  // ---- per-wave MFMA geometry (r1-validated 32x32x16 layouts) ----
  const size_t aoffE = (size_t)(Mtile * 32 + (lane & 31)) * 1024
                     + (size_t)(quarter & 1) * 512 + (size_t)(lane >> 5) * 8;  // elements
  const char* bB = (const char*)Wl + quarter * 32768 + (lane >> 5) * 512 + (lane & 31) * 16;
  float* slotp = &glds[wave >> 1][0][0];

  int seen0 = 0, seen1 = 0;

  __syncthreads();  // W staged (vmcnt drained by barrier)

  for (int t = 0; t < T_STEPS; ++t) {
    // ---- wave-level gates (dependency-exact; x-quarters run gate-free) ----
    const ushort* src;
    if (!isL1) {
      if (quarter < 2) src = p.xb + (size_t)t * BH;
      else { if (t > 0) { wgate(relOwn, t, seen0); src = p.h0r + (size_t)(t - 1) * BH; }
             else src = p.hinit; }
    } else {
      if (quarter < 2) { wgate(rel0, t + 1, seen0); src = p.h0r + (size_t)t * BH; }
      else { if (t > 0) { wgate(relOwn, t, seen1); src = p.h1r + (size_t)(t - 1) * BH; }
             else src = p.hinit + BH; }
    }

    f32x16 acc;
#pragma unroll
    for (int r = 0; r < 16; ++r) acc[r] = 0.f;
    short8 fr[16];
    const ushort* aPtr = src + aoffE;
    PIPE32X()

    // ---- deterministic pairwise K-reduction through LDS ----
    if (wave & 1) {
#pragma unroll
      for (int r = 0; r < 16; ++r)
        slotp[((r & 3) + 8 * (r >> 2) + 4 * (lane >> 5)) * 36 + (lane & 31)] = acc[r];
    }
    __syncthreads();
    if (!(wave & 1)) {
#pragma unroll
      for (int r = 0; r < 16; ++r)
        acc[r] += slotp[((r & 3) + 8 * (r >> 2) + 4 * (lane >> 5)) * 36 + (lane & 31)];
    }
    __syncthreads();
    if (!(wave & 1) && (wave & 2)) {  // waves 2,6 -> slots 0,1
      float* s2 = &glds[wave >> 2][0][0];
#pragma unroll
      for (int r = 0; r < 16; ++r)
        s2[((r & 3) + 8 * (r >> 2) + 4 * (lane >> 5)) * 36 + (lane & 31)] = acc[r];
    }
    __syncthreads();
    if ((wave & 3) == 0) {            // waves 0,4: final sum -> slots 2,3
      float* s2 = &glds[wave >> 2][0][0];
      float* sf = &glds[2 + (wave >> 2)][0][0];
#pragma unroll
      for (int r = 0; r < 16; ++r) {
        const int pr = (r & 3) + 8 * (r >> 2) + 4 * (lane >> 5);
        sf[pr * 36 + (lane & 31)] = acc[r] + s2[pr * 36 + (lane & 31)];
      }
    }
    __syncthreads();

    // ---- epilogue: one (b,j) per thread ----
    const float* gfin = &glds[2 + tile][0][0];
    const float vi = bias[0] + gfin[row * 36 + jl];
    const float vf = bias[1] + gfin[row * 36 + 8 + jl];
    const float vg = bias[2] + gfin[row * 36 + 16 + jl];
    const float vo = bias[3] + gfin[row * 36 + 24 + jl];
    float c = creg;
    const float si = 1.f / (1.f + __expf(-vi));
    const float sf_ = 1.f / (1.f + __expf(-vf));
    const float tg = tanhf(vg);
    const float so = 1.f / (1.f + __expf(-vo));
    c = sf_ * c + si * tg;
    const float h = so * tanhf(c);
    creg = c;

    // ---- h store (packed pairs) + same-address load-back (r5-proven) ----
    const uint32_t hu = (uint32_t)f2bf(h);
    const uint32_t other = __shfl_xor(hu, 1);
    ushort* hdst = (!isL1) ? (p.h0r + (size_t)t * BH) : (p.h1r + (size_t)t * BH);
    if (!(tid & 1)) {
      uint32_t* hw = (uint32_t*)(hdst + eb * 1024 + jj);
      const uint32_t packed = hu | (other << 16);
      __hip_atomic_store(hw, packed, __ATOMIC_RELAXED, __HIP_MEMORY_SCOPE_AGENT);
      uint32_t chk = __hip_atomic_load(hw, __ATOMIC_RELAXED, __HIP_MEMORY_SCOPE_AGENT);
      asm volatile("" :: "v"(chk));
    }

    if (isL1) {
      p.out[(size_t)t * BH + eb * 1024 + jj] = h;
      if (t == T_STEPS - 1) {
        p.out[(size_t)TBH + BH + eb * 1024 + jj] = h;
        p.out[(size_t)TBH + 3 * BH + eb * 1024 + jj] = c;
      }
    } else if (t == T_STEPS - 1) {
      p.out[(size_t)TBH + eb * 1024 + jj] = h;
      p.out[(size_t)TBH + 2 * BH + eb * 1024 + jj] = c;
    }

    __syncthreads();  // all load-backs done; LDS reads complete before reuse
    if (tid == 0) {
      __hip_atomic_fetch_add(gb + stripe * 16, 1, __ATOMIC_RELAXED, __HIP_MEMORY_SCOPE_AGENT);
      if (isRoot) {  // aggregate own group's arrivals, publish release = t+1
        const int need = (t + 1) * GBLK;
        for (;;) {
          int sum = 0;
#pragma unroll
          for (int i = 0; i < 16; ++i)
            sum += __hip_atomic_load(gb + i * 16, __ATOMIC_RELAXED, __HIP_MEMORY_SCOPE_AGENT);
          if (sum >= need) break;
          __builtin_amdgcn_s_sleep(1);
        }
        __hip_atomic_store((int*)relOwn, t + 1, __ATOMIC_RELAXED, __HIP_MEMORY_SCOPE_AGENT);
      }
    }
  }
}

// ---------------- host ----------------
extern "C" void kernel_launch(void* const* d_in, const int* in_sizes, int n_in,
                              void* d_out, int out_size, void* d_ws, size_t ws_size,
                              hipStream_t stream) {
  const float* x    = (const float*)d_in[0];
  const float* h0   = (const float*)d_in[1];
  const float* c0   = (const float*)d_in[2];
  const float* w_ih = (const float*)d_in[3];
  const float* w_hh = (const float*)d_in[4];
  const float* b_ih = (const float*)d_in[5];
  const float* b_hh = (const float*)d_in[6];
  float* out = (float*)d_out;

  ushort* xb    = (ushort*)d_ws;
  ushort* wihb  = xb + (size_t)TBH;
  ushort* whhb  = wihb + WEL;
  ushort* hinit = whhb + WEL;
  ushort* h0r   = hinit + 2 * (size_t)BH;            // ring: T_STEPS slots
  ushort* h1r   = h0r + (size_t)TBH;                 // ring: T_STEPS slots
  int*    bar   = (int*)(h1r + (size_t)TBH);

  const size_t need = ((size_t)3 * TBH + 2 * WEL + 2 * (size_t)BH) * 2 + 8192;
  if (ws_size < need) return;  // loud failure: d_out stays poisoned

  { int n = TBH;        k_f32_to_bf16<<<(n / 4 + 255) / 256, 256, 0, stream>>>(x, xb, n); }
  { int n = (int)WEL;   k_f32_to_bf16<<<(n / 4 + 255) / 256, 256, 0, stream>>>(w_ih, wihb, n); }
  { int n = (int)WEL;   k_f32_to_bf16<<<(n / 4 + 255) / 256, 256, 0, stream>>>(w_hh, whhb, n); }
  { int n = 2 * BH;     k_f32_to_bf16<<<(n / 4 + 255) / 256, 256, 0, stream>>>(h0, hinit, n); }
  k_zero<<<4, 256, 0, stream>>>(bar, 1024);

  ScanP sp;
  sp.wih = wihb; sp.whh = whhb;
  sp.xb = xb; sp.hinit = hinit;
  sp.h0r = h0r; sp.h1r = h1r;
  sp.c0 = c0; sp.bi = b_ih; sp.bh = b_hh;
  sp.out = out; sp.bar = bar;

  void* kp[1] = {&sp};
  hipLaunchCooperativeKernel(reinterpret_cast<void*>(&k_scan),
                             dim3(256), dim3(512), kp, 0, stream);
}